// Round 16
// baseline (46.362 us; speedup 1.0000x reference)
//
#include <hip/hip_runtime.h>
#include <math.h>
#include <float.h>

#define Bb 16
#define Nn 1000
#define NP 1024
#define Mm 24
#define Ss 72
#define Cc 78
#define Kk 10
#define NL 16                         // 16 lists (64-pred chunks) per column
#define INVALIDF (-100000.0f)
#define DEG2RAD 0.017453292519943295f

struct Hdr { int mask_mode; int pad0; int pad1; int pad2; };

// ---- primary ws layout (bytes); ws ~256 MiB ----
#define LSZ        (Bb*Mm*NL*Kk*4)                    // 245760
#define OFF_CHTOT  16
#define OFF_CHIDX  (OFF_CHTOT + LSZ)
#define OFF_CHIOU  (OFF_CHIDX + LSZ)
#define OFF_MOK    (OFF_CHIOU + LSZ)                  // int[384]
#define OFF_MSEL   (OFF_MOK + Bb*Mm*4)                // int[384*10]
#define OFF_MTOT   (OFF_MSEL + Bb*Mm*Kk*4)
#define OFF_MDK    (OFF_MTOT + Bb*Mm*Kk*4)            // int[384]
#define OFF_PMETA  ((OFF_MDK + Bb*Mm*4 + 255) & ~255)
#define OFF_PXS    (OFF_PMETA + Bb*NP*16)
#define WS7_NEEDED (OFF_PXS + Bb*Ss*NP*4)             // ~5.8 MB

__device__ __forceinline__ float read_dim(const void* p) {
    int v = *(const int*)p;
    if (v <= 0 || v > 1000000) v = (int)(*(const float*)p);
    return (float)v;
}

__device__ __forceinline__ bool mask_at(const void* m, int mode, int idx) {
    if (mode == 0) return ((const unsigned char*)m)[idx] != 0;
    if (mode == 1) return ((const int*)m)[idx] != 0;
    return ((const float*)m)[idx] != 0.0f;
}

// 64-lane bitonic sort, ascending by (v, i) lexicographic.
__device__ __forceinline__ void bitonic64(float& v, int& i, const int lane) {
#pragma unroll
    for (int k = 2; k <= 64; k <<= 1) {
#pragma unroll
        for (int j = k >> 1; j >= 1; j >>= 1) {
            const float pv = __shfl_xor(v, j, 64);
            const int   pi = __shfl_xor(i, j, 64);
            const bool keepMin = (((lane & k) == 0) == ((lane & j) == 0));
            const bool meLess  = (v < pv) || (v == pv && i < pi);
            if (keepMin ? !meLess : meLess) { v = pv; i = pi; }
        }
    }
}

// Value-only 64-lane bitonic sort (ascending) — for iou paths (indices unused).
__device__ __forceinline__ void bitonic64v(float& v, const int lane) {
#pragma unroll
    for (int k = 2; k <= 64; k <<= 1) {
#pragma unroll
        for (int j = k >> 1; j >= 1; j >>= 1) {
            const float pv = __shfl_xor(v, j, 64);
            const bool keepMin = (((lane & k) == 0) == ((lane & j) == 0));
            if (keepMin ? (pv < v) : (pv > v)) v = pv;
        }
    }
}

// ---------------------------------------------------------------------------
// k_prep2 (r15-proven verbatim): 512 blocks XCD-swizzled; pxs transposed
// [b][s][1024] + pmeta + mok[384]. Block q==0: parallel mask-dtype detect.
// ---------------------------------------------------------------------------
__global__ __launch_bounds__(256) void k_prep2(
    const float* __restrict__ preds, const unsigned char* __restrict__ mb,
    const void* __restrict__ hp,
    Hdr* __restrict__ hdr, int* __restrict__ mok,
    float* __restrict__ pxs, float4* __restrict__ pmeta)
{
    __shared__ float lds[32 * Cc];
    __shared__ float ys[Ss];
    __shared__ float ssx[32], ssy[32], sptan[32], slo[32];
    __shared__ int s_nz, s_f32;

    const int tid = threadIdx.x;
    const int q = blockIdx.x;
    const int L = ((q & 7) << 6) | (q >> 3);   // bijective: 512 % 8 == 0
    const int b   = L >> 5;
    const int blk = L & 31;
    const int base_n = blk * 32;
    const int valid = (base_n + 32 <= Nn) ? 32 : (Nn - base_n);   // 32 or 8

    const float4* src4 = (const float4*)(preds + ((size_t)b * Nn + base_n) * Cc);
    float4* lds4 = (float4*)lds;
    const int n4 = (valid * Cc) / 4;
    for (int i = tid; i < n4; i += 256) lds4[i] = src4[i];

    const float ih = read_dim(hp);
    if (tid < Ss)
        ys[tid] = (float)((double)(ih - 1.0f) * (double)(Ss - 1 - tid) / (double)(Ss - 1));

    if (q == 0) {
        if (tid == 0) { s_nz = 0; s_f32 = 0; }
        __syncthreads();
        if (tid < (Bb * Mm) / 4) {
            const uchar4 c4 = *(const uchar4*)(mb + tid * 4);
            int nz = (c4.y ? 1 : 0) + (c4.z ? 1 : 0) + (c4.w ? 1 : 0);
            bool f = (c4.x == 0x80 || c4.x == 0x3f) || (c4.y == 0x80 || c4.y == 0x3f) ||
                     (c4.z == 0x80 || c4.z == 0x3f) || (c4.w == 0x80 || c4.w == 0x3f);
            if (nz) atomicAdd(&s_nz, nz);
            if (f)  atomicOr(&s_f32, 1);
        }
        __syncthreads();
        const int mode = (s_nz == 0) ? 1 : (s_f32 ? 2 : 0);
        if (tid == 0) hdr->mask_mode = mode;
        for (int i = tid; i < Bb * Mm; i += 256)
            mok[i] = mask_at(mb, mode, i) ? 1 : 0;
    }
    __syncthreads();

    if (tid < valid) {
        const float* pr = lds + tid * Cc;
        const float p0 = pr[0], p1 = pr[1];
        const float sy = pr[2], sx = pr[3], th = pr[4], len = pr[5];
        const float mx = fmaxf(p0, p1);
        const float e0 = expf(p0 - mx), e1 = expf(p1 - mx);
        float score = fmaxf(e1 / (e0 + e1), 1e-8f);
        const float cls = -logf(score);
        ssx[tid] = sx; ssy[tid] = sy;
        sptan[tid] = fminf(fmaxf(tanf(th * DEG2RAD), -1000.0f), 1000.0f);
        slo[tid] = sy - len;
        pmeta[(b << 10) | (base_n + tid)] = make_float4(cls, sx, sy, th);
    }
    __syncthreads();

    const int nn = tid & 31, srow = tid >> 5;
    if (nn < valid) {
        const int n = base_n + nn;
        const float sx = ssx[nn], sy = ssy[nn], ptan = sptan[nn], lo = slo[nn];
        const float* dxr = lds + nn * Cc + 6;
        for (int s = srow; s < Ss; s += 8) {
            const float y = ys[s];
            const float px = sx + (sy - y) * ptan + dxr[s];
            const bool valid_s = (y >= lo) && (y <= sy);
            pxs[(((size_t)b * Ss + s) << 10) | n] = valid_s ? px : INVALIDF;
        }
    }
}

// ---------------------------------------------------------------------------
// k_colJ: 3072 blocks x 128 thr, XCD-swizzled. Each WAVE owns a 64-pred
// chunk: compute (r14-proven staged accumulation, bit-identical), ONE tot
// bitonic + ONE iou value-bitonic, write its sorted 10-list directly to
// global. No intra-block merge, no post-sort barrier — minimal serial chain.
// chiou stores NEGATED iou (ascending); k_merge is the only consumer.
// ---------------------------------------------------------------------------
__global__ __launch_bounds__(128) void k_colJ(
    const float* __restrict__ targs, const int* __restrict__ mok,
    const float* __restrict__ pxs, const float4* __restrict__ pmeta,
    const void* __restrict__ wp, const void* __restrict__ hp,
    float* __restrict__ chtot, int* __restrict__ chidx, float* __restrict__ chiou)
{
    __shared__ float gx[Ss];

    const int P = blockIdx.x;
    const int L = (P & 7) * 384 + (P >> 3);    // bijective: 3072 % 8 == 0
    const int col   = L >> 3;                  // b*Mm + m
    const int cpair = L & 7;                   // chunk pair
    const int b     = col / Mm;
    const int tid   = threadIdx.x;

    if (!mok[col]) return;                     // merge re-checks mask

    const float iw = read_dim(wp);
    const float ih = read_dim(hp);
    const float* tg = targs + (size_t)col * Cc;
    const float g_sy = tg[2], g_sx = tg[3], g_th = tg[4];
    const float g_tan = fminf(fmaxf(tanf(g_th * DEG2RAD), -1000.0f), 1000.0f);

    if (tid < Ss) {
        const float y = (float)((double)(ih - 1.0f) * (double)(Ss - 1 - tid) / (double)(Ss - 1));
        const float gdx = tg[6 + tid];
        float v = g_sx + (g_sy - y) * g_tan + gdx;
        if (gdx < -10000.0f || v < 0.0f || v >= iw) v = INVALIDF;
        gx[tid] = v;
    }
    __syncthreads();

    const int w = tid >> 6, lane = tid & 63;
    const int chunk = cpair * 2 + w;           // 0..15
    const int n = (chunk << 6) | lane;         // 0..1023 (pad if >= Nn)

    float ov = 0.0f, un = 0.0f;
    const float* pxb = pxs + (((size_t)b * Ss) << 10);
#pragma unroll
    for (int bat = 0; bat < 3; ++bat) {        // 3 x 24 register-staged batches
        float pxr[24];
#pragma unroll
        for (int u = 0; u < 24; ++u)
            pxr[u] = pxb[((bat * 24 + u) << 10) | n];
#pragma unroll
        for (int u = 0; u < 24; ++u) {         // exact s-order accumulation
            const float g = gx[bat * 24 + u];
            const float px = pxr[u];
            if (g != INVALIDF && px != INVALIDF) {
                const float d = fabsf(px - g);
                ov += 30.0f - d;
                un += 30.0f + d;
            }
        }
    }

    const float4 me = pmeta[(b << 10) + n];
    const float iouv = ov / (un + 1e-9f);
    const float dxn = (me.y - g_sx) / (iw - 1.0f);
    const float dyn = (me.z - g_sy) / (ih - 1.0f);
    const float dist = sqrtf(dxn * dxn + dyn * dyn + 1e-8f);
    const float theta = fabsf((me.w - g_th) / 90.0f);
    const float geom = 1.0f * dist + 2.0f * theta;
    const float t = 4.0f * me.x + 5.0f * geom + 2.0f * (1.0f - iouv);

    const int obase = col * (NL * Kk) + chunk * Kk;

    float v1 = (n < Nn) ? t : FLT_MAX;     int i1 = n;
    bitonic64(v1, i1, lane);
    if (lane < Kk) { chtot[obase + lane] = v1; chidx[obase + lane] = i1; }

    float v2 = (n < Nn) ? -iouv : FLT_MAX;
    bitonic64v(v2, lane);
    if (lane < Kk) chiou[obase + lane] = v2;   // negated, ascending
}

// ---------------------------------------------------------------------------
// k_merge: 384 blocks x 128 thr (one column each, XCD-swizzled). Wave 0
// merges the 16 tot-lists (4x 40-candidate sorts -> gather -> final sort;
// exact by k-way selection over the (v,idx) total order). Wave 1: same on
// negated iou values + desc-order sum -> dynamic_k.
// ---------------------------------------------------------------------------
__global__ __launch_bounds__(128) void k_merge(
    const int* __restrict__ mok,
    const float* __restrict__ chtot, const int* __restrict__ chidx,
    const float* __restrict__ chiou,
    int* __restrict__ msel, float* __restrict__ mtot, int* __restrict__ mdk)
{
    const int P = blockIdx.x;
    const int col = (P & 7) * 48 + (P >> 3);   // bijective: 384 % 8 == 0
    const int tid = threadIdx.x;
    const int w = tid >> 6, lane = tid & 63;

    if (!mok[col]) {
        if (tid == 0) mdk[col] = 0;
        return;
    }
    const int base = col * (NL * Kk);
    const int g = lane / 10, o = lane - g * 10;   // gather coords (g<4 used)

    if (w == 0) {
        float tA, tB, tC, tD; int iA, iB, iC, iD;
        tA = (lane < 40) ? chtot[base + lane]       : FLT_MAX;
        iA = (lane < 40) ? chidx[base + lane]       : 0x7fffffff;
        bitonic64(tA, iA, lane);
        tB = (lane < 40) ? chtot[base + 40 + lane]  : FLT_MAX;
        iB = (lane < 40) ? chidx[base + 40 + lane]  : 0x7fffffff;
        bitonic64(tB, iB, lane);
        tC = (lane < 40) ? chtot[base + 80 + lane]  : FLT_MAX;
        iC = (lane < 40) ? chidx[base + 80 + lane]  : 0x7fffffff;
        bitonic64(tC, iC, lane);
        tD = (lane < 40) ? chtot[base + 120 + lane] : FLT_MAX;
        iD = (lane < 40) ? chidx[base + 120 + lane] : 0x7fffffff;
        bitonic64(tD, iD, lane);

        const float vA = __shfl(tA, o, 64), vB = __shfl(tB, o, 64);
        const float vC = __shfl(tC, o, 64), vD = __shfl(tD, o, 64);
        const int   jA = __shfl(iA, o, 64), jB = __shfl(iB, o, 64);
        const int   jC = __shfl(iC, o, 64), jD = __shfl(iD, o, 64);
        float v = FLT_MAX; int i = 0x7fffffff;
        if      (g == 0) { v = vA; i = jA; }
        else if (g == 1) { v = vB; i = jB; }
        else if (g == 2) { v = vC; i = jC; }
        else if (g == 3) { v = vD; i = jD; }
        bitonic64(v, i, lane);
        if (lane < Kk) { msel[col * Kk + lane] = i; mtot[col * Kk + lane] = v; }
    } else {
        float tA, tB, tC, tD;
        tA = (lane < 40) ? chiou[base + lane]       : FLT_MAX;  bitonic64v(tA, lane);
        tB = (lane < 40) ? chiou[base + 40 + lane]  : FLT_MAX;  bitonic64v(tB, lane);
        tC = (lane < 40) ? chiou[base + 80 + lane]  : FLT_MAX;  bitonic64v(tC, lane);
        tD = (lane < 40) ? chiou[base + 120 + lane] : FLT_MAX;  bitonic64v(tD, lane);

        const float vA = __shfl(tA, o, 64), vB = __shfl(tB, o, 64);
        const float vC = __shfl(tC, o, 64), vD = __shfl(tD, o, 64);
        float v = FLT_MAX;
        if      (g == 0) v = vA;
        else if (g == 1) v = vB;
        else if (g == 2) v = vC;
        else if (g == 3) v = vD;
        bitonic64v(v, lane);                       // ascending negated = desc actual
        float isum = 0.0f;
#pragma unroll
        for (int k = 0; k < Kk; ++k) isum += -__shfl(v, k, 64);
        if (lane == 0) {
            int dk = (int)isum;                    // astype(int32): trunc
            dk = (dk < 1) ? 1 : (dk > Kk ? Kk : dk);
            mdk[col] = dk;
        }
    }
}

// ---------------------------------------------------------------------------
// k_resolve4: one block per batch (1024 thr). Stage merged lists (tiny),
// per-pred conflict resolution (r15-proven loop), write out.
// ---------------------------------------------------------------------------
__global__ __launch_bounds__(1024) void k_resolve4(
    const int* __restrict__ msel, const float* __restrict__ mtot,
    const int* __restrict__ mdk, int* __restrict__ out)
{
    __shared__ int   s_sel[Mm * Kk];
    __shared__ float s_tot[Mm * Kk];
    __shared__ int   s_dk[Mm];

    const int b   = blockIdx.x;
    const int tid = threadIdx.x;

    if (tid < Mm * Kk) {
        s_sel[tid] = msel[b * Mm * Kk + tid];
        s_tot[tid] = mtot[b * Mm * Kk + tid];
    }
    if (tid < Mm) s_dk[tid] = mdk[b * Mm + tid];
    __syncthreads();

    if (tid < Nn) {
        const int n = tid;
        int cnt = 0, firstm = -1, bestm = -1;
        float bestv = FLT_MAX;
        for (int m = 0; m < Mm; ++m) {
            const int dk = s_dk[m];
            for (int k = 0; k < dk; ++k) {
                if (s_sel[m * Kk + k] == n) {
                    const float tv = s_tot[m * Kk + k];
                    cnt++;
                    if (firstm < 0) firstm = m;
                    if (tv < bestv) { bestv = tv; bestm = m; }
                    break;
                }
            }
        }
        int matched;
        if (cnt == 0)      matched = -1;
        else if (cnt == 1) matched = firstm;
        else               matched = bestm;

        const int gid = b * Nn + n;
        out[gid]           = (cnt > 0) ? 1 : 0;
        out[Bb * Nn + gid] = matched;
    }
}

// ===========================================================================
// Fallback (proven round-2 path) if ws is unexpectedly small.
// ===========================================================================
#define OFF_FSELK   16
#define OFF_FSELTOT (OFF_FSELK + Bb*Mm*Kk*4)
#define OFF_FDYNK   (OFF_FSELTOT + Bb*Mm*Kk*4)

__global__ void k_detect_fb(const unsigned char* __restrict__ mb, Hdr* __restrict__ hdr) {
    int nz_off = 0; bool f32pat = false;
    for (int i = 0; i < Bb * Mm; ++i) {
        unsigned char c = mb[i];
        if ((i & 3) && c) nz_off++;
        if (c == 0x80 || c == 0x3f) f32pat = true;
    }
    hdr->mask_mode = (nz_off == 0) ? 1 : (f32pat ? 2 : 0);
}

__global__ __launch_bounds__(256) void k_col_fb(
    const float* __restrict__ preds, const float* __restrict__ targs,
    const void* __restrict__ masks, const Hdr* __restrict__ hdr,
    const void* __restrict__ wp, const void* __restrict__ hp,
    int* __restrict__ selk, float* __restrict__ seltot, int* __restrict__ dynk)
{
    __shared__ float ys[Ss];
    __shared__ float gx[Ss];
    __shared__ float iou_s[Nn];
    __shared__ float tot_s[Nn];
    __shared__ float rv[256];
    __shared__ int   ri[256];

    const int bm = blockIdx.x;
    const int b  = bm / Mm;
    const int tid = threadIdx.x;
    const float iw = read_dim(wp);
    const float ih = read_dim(hp);

    if (!mask_at(masks, hdr->mask_mode, bm)) {
        if (tid == 0) dynk[bm] = 0;
        return;
    }
    if (tid < Ss)
        ys[tid] = (float)((double)(ih - 1.0f) * (double)(Ss - 1 - tid) / (double)(Ss - 1));
    __syncthreads();

    const float* tg = targs + (size_t)bm * Cc;
    const float g_sy = tg[2], g_sx = tg[3], g_th = tg[4];
    const float g_tan = fminf(fmaxf(tanf(g_th * DEG2RAD), -1000.0f), 1000.0f);
    if (tid < Ss) {
        float gdx = tg[6 + tid];
        float v = g_sx + (g_sy - ys[tid]) * g_tan + gdx;
        if (gdx < -10000.0f || v < 0.0f || v >= iw) v = INVALIDF;
        gx[tid] = v;
    }
    __syncthreads();

    for (int n = tid; n < Nn; n += 256) {
        const float* pr = preds + ((size_t)b * Nn + n) * Cc;
        const float p0 = pr[0], p1 = pr[1];
        const float sy = pr[2], sx = pr[3], th = pr[4], len = pr[5];
        const float mx = fmaxf(p0, p1);
        const float e0 = expf(p0 - mx), e1 = expf(p1 - mx);
        float score = fmaxf(e1 / (e0 + e1), 1e-8f);
        const float cls = -logf(score);
        const float ptan = fminf(fmaxf(tanf(th * DEG2RAD), -1000.0f), 1000.0f);
        const float lo = sy - len;
        float ov = 0.0f, un = 0.0f;
        for (int s = 0; s < Ss; ++s) {
            const float y = ys[s];
            const float t = gx[s];
            if (y >= lo && y <= sy && t != INVALIDF) {
                const float px = sx + (sy - y) * ptan + pr[6 + s];
                if (px != INVALIDF) {
                    const float d = fabsf(px - t);
                    ov += 30.0f - d;
                    un += 30.0f + d;
                }
            }
        }
        const float iou = ov / (un + 1e-9f);
        const float dxn = (sx - g_sx) / (iw - 1.0f);
        const float dyn = (sy - g_sy) / (ih - 1.0f);
        const float dist = sqrtf(dxn * dxn + dyn * dyn + 1e-8f);
        const float theta = fabsf((th - g_th) / 90.0f);
        const float tot = 4.0f * cls + 5.0f * (1.0f * dist + 2.0f * theta) + 2.0f * (1.0f - iou);
        iou_s[n] = iou;
        tot_s[n] = tot;
    }
    __syncthreads();

    for (int k = 0; k < Kk; ++k) {
        float bv = FLT_MAX; int bi = 0x7fffffff;
        for (int n = tid; n < Nn; n += 256) {
            const float v = tot_s[n];
            if (v < bv) { bv = v; bi = n; }
        }
        rv[tid] = bv; ri[tid] = bi;
        __syncthreads();
        for (int off = 128; off > 0; off >>= 1) {
            if (tid < off) {
                const float v2 = rv[tid + off]; const int i2 = ri[tid + off];
                if (v2 < rv[tid] || (v2 == rv[tid] && i2 < ri[tid])) { rv[tid] = v2; ri[tid] = i2; }
            }
            __syncthreads();
        }
        if (tid == 0) {
            const int c = ri[0];
            selk[bm * Kk + k] = c;
            seltot[bm * Kk + k] = tot_s[c];
            tot_s[c] = FLT_MAX;
        }
        __syncthreads();
    }

    float isum = 0.0f;
    for (int k = 0; k < Kk; ++k) {
        float bv = -FLT_MAX; int bi = 0x7fffffff;
        for (int n = tid; n < Nn; n += 256) {
            const float v = iou_s[n];
            if (v > bv) { bv = v; bi = n; }
        }
        rv[tid] = bv; ri[tid] = bi;
        __syncthreads();
        for (int off = 128; off > 0; off >>= 1) {
            if (tid < off) {
                const float v2 = rv[tid + off]; const int i2 = ri[tid + off];
                if (v2 > rv[tid] || (v2 == rv[tid] && i2 < ri[tid])) { rv[tid] = v2; ri[tid] = i2; }
            }
            __syncthreads();
        }
        if (tid == 0) {
            const int c = ri[0];
            isum += iou_s[c];
            iou_s[c] = -FLT_MAX;
        }
        __syncthreads();
    }
    if (tid == 0) {
        int dk = (int)isum;
        dk = (dk < 1) ? 1 : (dk > Nn ? Nn : dk);
        dynk[bm] = dk;
    }
}

__global__ __launch_bounds__(256) void k_resolve_fb(
    const int* __restrict__ selk, const float* __restrict__ seltot,
    const int* __restrict__ dynk, int* __restrict__ out)
{
    const int gid = blockIdx.x * 256 + threadIdx.x;
    if (gid >= Bb * Nn) return;
    const int b = gid / Nn;
    const int n = gid % Nn;

    int cnt = 0, firstm = -1, bestm = -1;
    float bestv = FLT_MAX;
    for (int m = 0; m < Mm; ++m) {
        const int bm = b * Mm + m;
        const int dk = dynk[bm];
        for (int k = 0; k < dk && k < Kk; ++k) {
            if (selk[bm * Kk + k] == n) {
                const float tv = seltot[bm * Kk + k];
                cnt++;
                if (firstm < 0) firstm = m;
                if (tv < bestv) { bestv = tv; bestm = m; }
                break;
            }
        }
    }
    int matched;
    if (cnt == 0)      matched = -1;
    else if (cnt == 1) matched = firstm;
    else               matched = bestm;

    out[gid]           = (cnt > 0) ? 1 : 0;
    out[Bb * Nn + gid] = matched;
}

extern "C" void kernel_launch(void* const* d_in, const int* in_sizes, int n_in,
                              void* d_out, int out_size, void* d_ws, size_t ws_size,
                              hipStream_t stream) {
    const float* preds = (const float*)d_in[0];
    const float* targs = (const float*)d_in[1];
    const void*  masks = d_in[2];
    const void*  wp    = d_in[3];
    const void*  hp    = d_in[4];
    int* out = (int*)d_out;

    char* ws = (char*)d_ws;
    Hdr* hdr = (Hdr*)ws;

    if (ws_size >= (size_t)WS7_NEEDED) {
        float*  chtot = (float*)(ws + OFF_CHTOT);
        int*    chidx = (int*)(ws + OFF_CHIDX);
        float*  chiou = (float*)(ws + OFF_CHIOU);
        int*    mok   = (int*)(ws + OFF_MOK);
        int*    msel  = (int*)(ws + OFF_MSEL);
        float*  mtot  = (float*)(ws + OFF_MTOT);
        int*    mdk   = (int*)(ws + OFF_MDK);
        float4* pmeta = (float4*)(ws + OFF_PMETA);
        float*  pxs   = (float*)(ws + OFF_PXS);

        k_prep2<<<512, 256, 0, stream>>>(preds, (const unsigned char*)masks, hp,
                                         hdr, mok, pxs, pmeta);
        k_colJ<<<Bb * Mm * 8, 128, 0, stream>>>(targs, mok, pxs, pmeta,
                                                wp, hp, chtot, chidx, chiou);
        k_merge<<<Bb * Mm, 128, 0, stream>>>(mok, chtot, chidx, chiou,
                                             msel, mtot, mdk);
        k_resolve4<<<Bb, 1024, 0, stream>>>(msel, mtot, mdk, out);
    } else {
        int*   selk   = (int*)(ws + OFF_FSELK);
        float* seltot = (float*)(ws + OFF_FSELTOT);
        int*   dynk   = (int*)(ws + OFF_FDYNK);
        k_detect_fb<<<1, 1, 0, stream>>>((const unsigned char*)masks, hdr);
        k_col_fb<<<Bb * Mm, 256, 0, stream>>>(preds, targs, masks, hdr, wp, hp,
                                              selk, seltot, dynk);
        k_resolve_fb<<<(Bb * Nn + 255) / 256, 256, 0, stream>>>(selk, seltot, dynk, out);
    }
}

// Round 17
// 43.972 us; speedup vs baseline: 1.0544x; 1.0544x over previous
//
#include <hip/hip_runtime.h>
#include <math.h>
#include <float.h>

#define Bb 16
#define Nn 1000
#define NP 1024
#define Mm 24
#define Ss 72
#define Cc 78
#define Kk 10
#define NCH 4
#define INVALIDF (-100000.0f)
#define DEG2RAD 0.017453292519943295f

struct Hdr { int mask_mode; int pad0; int pad1; int pad2; };

// ---- primary ws layout (bytes); ws ~256 MiB ----
#define CHSZ       (Bb*Mm*NCH*Kk*4)                   // 61440
#define OFF_CHTOT  16
#define OFF_CHIDX  (OFF_CHTOT + CHSZ)
#define OFF_CHIOU  (OFF_CHIDX + CHSZ)
#define OFF_PMETA  ((OFF_CHIOU + CHSZ + 255) & ~255)
#define OFF_PXS    (OFF_PMETA + Bb*NP*16)
#define WS6_NEEDED (OFF_PXS + Bb*Ss*NP*4)             // ~5.2 MB

__device__ __forceinline__ float read_dim(const void* p) {
    int v = *(const int*)p;
    if (v <= 0 || v > 1000000) v = (int)(*(const float*)p);
    return (float)v;
}

__device__ __forceinline__ bool mask_at(const void* m, int mode, int idx) {
    if (mode == 0) return ((const unsigned char*)m)[idx] != 0;
    if (mode == 1) return ((const int*)m)[idx] != 0;
    return ((const float*)m)[idx] != 0.0f;
}

// 64-lane bitonic sort, ascending by (v, i) lexicographic. 21 shfl_xor stages.
__device__ __forceinline__ void bitonic64(float& v, int& i, const int lane) {
#pragma unroll
    for (int k = 2; k <= 64; k <<= 1) {
#pragma unroll
        for (int j = k >> 1; j >= 1; j >>= 1) {
            const float pv = __shfl_xor(v, j, 64);
            const int   pi = __shfl_xor(i, j, 64);
            const bool keepMin = (((lane & k) == 0) == ((lane & j) == 0));
            const bool meLess  = (v < pv) || (v == pv && i < pi);
            if (keepMin ? !meLess : meLess) { v = pv; i = pi; }
        }
    }
}

// ---------------------------------------------------------------------------
// k_prep2 (r12-proven verbatim): 512 blocks XCD-swizzled; 32 preds/block ->
// pxs transposed [b][s][1024] + pmeta(cls,sx,sy,th). Block q==0: parallel
// mask-dtype detect.
// ---------------------------------------------------------------------------
__global__ __launch_bounds__(256) void k_prep2(
    const float* __restrict__ preds, const unsigned char* __restrict__ mb,
    const void* __restrict__ hp,
    Hdr* __restrict__ hdr, float* __restrict__ pxs, float4* __restrict__ pmeta)
{
    __shared__ float lds[32 * Cc];
    __shared__ float ys[Ss];
    __shared__ float ssx[32], ssy[32], sptan[32], slo[32];
    __shared__ int s_nz, s_f32;

    const int tid = threadIdx.x;
    const int q = blockIdx.x;
    const int L = ((q & 7) << 6) | (q >> 3);   // bijective: 512 % 8 == 0
    const int b   = L >> 5;
    const int blk = L & 31;
    const int base_n = blk * 32;
    const int valid = (base_n + 32 <= Nn) ? 32 : (Nn - base_n);   // 32 or 8

    const float4* src4 = (const float4*)(preds + ((size_t)b * Nn + base_n) * Cc);
    float4* lds4 = (float4*)lds;
    const int n4 = (valid * Cc) / 4;
    for (int i = tid; i < n4; i += 256) lds4[i] = src4[i];

    const float ih = read_dim(hp);
    if (tid < Ss)
        ys[tid] = (float)((double)(ih - 1.0f) * (double)(Ss - 1 - tid) / (double)(Ss - 1));

    if (q == 0) {
        if (tid == 0) { s_nz = 0; s_f32 = 0; }
        __syncthreads();
        if (tid < (Bb * Mm) / 4) {
            const uchar4 c4 = *(const uchar4*)(mb + tid * 4);
            int nz = (c4.y ? 1 : 0) + (c4.z ? 1 : 0) + (c4.w ? 1 : 0);
            bool f = (c4.x == 0x80 || c4.x == 0x3f) || (c4.y == 0x80 || c4.y == 0x3f) ||
                     (c4.z == 0x80 || c4.z == 0x3f) || (c4.w == 0x80 || c4.w == 0x3f);
            if (nz) atomicAdd(&s_nz, nz);
            if (f)  atomicOr(&s_f32, 1);
        }
        __syncthreads();
        if (tid == 0)
            hdr->mask_mode = (s_nz == 0) ? 1 : (s_f32 ? 2 : 0);
    }
    __syncthreads();

    if (tid < valid) {
        const float* pr = lds + tid * Cc;
        const float p0 = pr[0], p1 = pr[1];
        const float sy = pr[2], sx = pr[3], th = pr[4], len = pr[5];
        const float mx = fmaxf(p0, p1);
        const float e0 = expf(p0 - mx), e1 = expf(p1 - mx);
        float score = fmaxf(e1 / (e0 + e1), 1e-8f);
        const float cls = -logf(score);
        ssx[tid] = sx; ssy[tid] = sy;
        sptan[tid] = fminf(fmaxf(tanf(th * DEG2RAD), -1000.0f), 1000.0f);
        slo[tid] = sy - len;
        pmeta[(b << 10) | (base_n + tid)] = make_float4(cls, sx, sy, th);
    }
    __syncthreads();

    const int nn = tid & 31, srow = tid >> 5;
    if (nn < valid) {
        const int n = base_n + nn;
        const float sx = ssx[nn], sy = ssy[nn], ptan = sptan[nn], lo = slo[nn];
        const float* dxr = lds + nn * Cc + 6;
        for (int s = srow; s < Ss; s += 8) {
            const float y = ys[s];
            const float px = sx + (sy - y) * ptan + dxr[s];
            const bool valid_s = (y >= lo) && (y <= sy);
            pxs[(((size_t)b * Ss + s) << 10) | n] = valid_s ? px : INVALIDF;
        }
    }
}

// ---------------------------------------------------------------------------
// k_colE3 (r14-proven verbatim): 1536 blocks XCD-swizzled; 3x24 register-
// staged load batches; per-wave bitonic top-10 x2; 2 concurrent wave merges.
// ---------------------------------------------------------------------------
__global__ __launch_bounds__(256) void k_colE3(
    const float* __restrict__ targs, const void* __restrict__ masks,
    const Hdr* __restrict__ hdr, const float* __restrict__ pxs,
    const float4* __restrict__ pmeta, const void* __restrict__ wp,
    const void* __restrict__ hp,
    float* __restrict__ chtot, int* __restrict__ chidx, float* __restrict__ chiou)
{
    __shared__ float gx[Ss];
    __shared__ float wtot[4][Kk];
    __shared__ int   widx[4][Kk];
    __shared__ float wiou[4][Kk];          // negated iou, ascending

    const int P = blockIdx.x;
    const int L = (P & 7) * 192 + (P >> 3);    // bijective: 1536 % 8 == 0
    const int col   = L >> 2;                  // b*Mm + m
    const int chunk = L & 3;
    const int b     = col / Mm;                // batch -> XCD b/2
    const int tid   = threadIdx.x;

    if (!mask_at(masks, hdr->mask_mode, col)) return;   // k_final re-checks mask

    const float iw = read_dim(wp);
    const float ih = read_dim(hp);
    const float* tg = targs + (size_t)col * Cc;
    const float g_sy = tg[2], g_sx = tg[3], g_th = tg[4];
    const float g_tan = fminf(fmaxf(tanf(g_th * DEG2RAD), -1000.0f), 1000.0f);

    if (tid < Ss) {
        const float y = (float)((double)(ih - 1.0f) * (double)(Ss - 1 - tid) / (double)(Ss - 1));
        const float gdx = tg[6 + tid];
        float v = g_sx + (g_sy - y) * g_tan + gdx;
        if (gdx < -10000.0f || v < 0.0f || v >= iw) v = INVALIDF;
        gx[tid] = v;
    }
    __syncthreads();

    const int n = chunk * 256 + tid;       // global pred index (pad if >= Nn)
    float ov = 0.0f, un = 0.0f;
    const float* pxb = pxs + (((size_t)b * Ss) << 10);
#pragma unroll
    for (int bat = 0; bat < 3; ++bat) {    // 3 x 24 register-staged batches
        float pxr[24];
#pragma unroll
        for (int u = 0; u < 24; ++u)       // 24 loads in flight
            pxr[u] = pxb[((bat * 24 + u) << 10) | n];
#pragma unroll
        for (int u = 0; u < 24; ++u) {     // exact s-order accumulation
            const float g = gx[bat * 24 + u];
            const float px = pxr[u];
            if (g != INVALIDF && px != INVALIDF) {
                const float d = fabsf(px - g);
                ov += 30.0f - d;
                un += 30.0f + d;
            }
        }
    }

    const float4 me = pmeta[(b << 10) + n];
    const float iouv = ov / (un + 1e-9f);
    const float dxn = (me.y - g_sx) / (iw - 1.0f);
    const float dyn = (me.z - g_sy) / (ih - 1.0f);
    const float dist = sqrtf(dxn * dxn + dyn * dyn + 1e-8f);
    const float theta = fabsf((me.w - g_th) / 90.0f);
    const float geom = 1.0f * dist + 2.0f * theta;
    const float t = 4.0f * me.x + 5.0f * geom + 2.0f * (1.0f - iouv);

    const int w = tid >> 6, lane = tid & 63;

    // ---- per-wave sorted top-10 via one bitonic sort each ----
    float v1 = (n < Nn) ? t : FLT_MAX;     int i1 = n;
    bitonic64(v1, i1, lane);
    if (lane < Kk) { wtot[w][lane] = v1; widx[w][lane] = i1; }

    float v2 = (n < Nn) ? -iouv : FLT_MAX; int i2 = n;
    bitonic64(v2, i2, lane);
    if (lane < Kk) wiou[w][lane] = v2;     // negated; lanes 0-9 = 10 largest iou
    __syncthreads();

    const int obase = L * Kk;              // == (col*NCH+chunk)*Kk
    if (w == 0) {                          // merge 40 tot candidates
        float v = FLT_MAX; int i = 0x7fffffff;
        if (lane < NCH * Kk) { v = wtot[lane / Kk][lane % Kk]; i = widx[lane / Kk][lane % Kk]; }
        bitonic64(v, i, lane);
        if (lane < Kk) { chtot[obase + lane] = v; chidx[obase + lane] = i; }
    } else if (w == 1) {                   // merge 40 iou candidates (concurrent)
        float v = FLT_MAX; int i = lane;
        if (lane < NCH * Kk) v = wiou[lane / Kk][lane % Kk];
        bitonic64(v, i, lane);
        if (lane < Kk) chiou[obase + lane] = -v;   // actual iou, sorted desc
    }
}

// ---------------------------------------------------------------------------
// k_final (r9-proven verbatim): one block per batch (1024 thr = 16 waves).
// Wave-parallel column merges + sequential-desc iou sum -> dynamic_k, then
// per-pred conflict resolution and output.
// ---------------------------------------------------------------------------
__global__ __launch_bounds__(1024) void k_final(
    const void* __restrict__ masks, const Hdr* __restrict__ hdr,
    const float* __restrict__ chtot, const int* __restrict__ chidx,
    const float* __restrict__ chiou, int* __restrict__ out)
{
    __shared__ float stot[Mm * NCH * Kk];   // 960
    __shared__ int   sidx[Mm * NCH * Kk];
    __shared__ float siou[Mm * NCH * Kk];
    __shared__ int   s_sel[Mm * Kk];
    __shared__ float s_tot[Mm * Kk];
    __shared__ int   s_dk[Mm];
    __shared__ int   maskok[Mm];

    const int b   = blockIdx.x;
    const int tid = threadIdx.x;
    const int mode = hdr->mask_mode;

    const int bbase = b * (Mm * NCH * Kk);
    if (tid < Mm * NCH * Kk) {
        stot[tid] = chtot[bbase + tid];
        sidx[tid] = chidx[bbase + tid];
        siou[tid] = chiou[bbase + tid];
    }
    if (tid < Mm) maskok[tid] = mask_at(masks, mode, b * Mm + tid) ? 1 : 0;
    __syncthreads();

    const int w = tid >> 6, lane = tid & 63;
    for (int m = w; m < Mm; m += 16) {
        if (!maskok[m]) {
            if (lane == 0) s_dk[m] = 0;
            continue;
        }
        float v = FLT_MAX; int i = 0x7fffffff;
        if (lane < NCH * Kk) { v = stot[m * NCH * Kk + lane]; i = sidx[m * NCH * Kk + lane]; }
        bitonic64(v, i, lane);
        if (lane < Kk) { s_sel[m * Kk + lane] = i; s_tot[m * Kk + lane] = v; }

        float v2 = FLT_MAX; int i2 = lane;
        if (lane < NCH * Kk) v2 = -siou[m * NCH * Kk + lane];
        bitonic64(v2, i2, lane);
        float isum = 0.0f;
#pragma unroll
        for (int k = 0; k < Kk; ++k) isum += -__shfl(v2, k, 64);
        if (lane == 0) {
            int dk = (int)isum;                       // astype(int32): trunc
            dk = (dk < 1) ? 1 : (dk > Kk ? Kk : dk);  // sum of 10 ious <= 10
            s_dk[m] = dk;
        }
    }
    __syncthreads();

    if (tid < Nn) {
        const int n = tid;
        int cnt = 0, firstm = -1, bestm = -1;
        float bestv = FLT_MAX;
        for (int m = 0; m < Mm; ++m) {
            const int dk = s_dk[m];
            for (int k = 0; k < dk; ++k) {
                if (s_sel[m * Kk + k] == n) {
                    const float tv = s_tot[m * Kk + k];
                    cnt++;
                    if (firstm < 0) firstm = m;
                    if (tv < bestv) { bestv = tv; bestm = m; }
                    break;
                }
            }
        }
        int matched;
        if (cnt == 0)      matched = -1;
        else if (cnt == 1) matched = firstm;
        else               matched = bestm;

        const int gid = b * Nn + n;
        out[gid]           = (cnt > 0) ? 1 : 0;
        out[Bb * Nn + gid] = matched;
    }
}

// ===========================================================================
// Fallback (proven round-2 path) if ws is unexpectedly small.
// ===========================================================================
#define OFF_FSELK   16
#define OFF_FSELTOT (OFF_FSELK + Bb*Mm*Kk*4)
#define OFF_FDYNK   (OFF_FSELTOT + Bb*Mm*Kk*4)

__global__ void k_detect_fb(const unsigned char* __restrict__ mb, Hdr* __restrict__ hdr) {
    int nz_off = 0; bool f32pat = false;
    for (int i = 0; i < Bb * Mm; ++i) {
        unsigned char c = mb[i];
        if ((i & 3) && c) nz_off++;
        if (c == 0x80 || c == 0x3f) f32pat = true;
    }
    hdr->mask_mode = (nz_off == 0) ? 1 : (f32pat ? 2 : 0);
}

__global__ __launch_bounds__(256) void k_col_fb(
    const float* __restrict__ preds, const float* __restrict__ targs,
    const void* __restrict__ masks, const Hdr* __restrict__ hdr,
    const void* __restrict__ wp, const void* __restrict__ hp,
    int* __restrict__ selk, float* __restrict__ seltot, int* __restrict__ dynk)
{
    __shared__ float ys[Ss];
    __shared__ float gx[Ss];
    __shared__ float iou_s[Nn];
    __shared__ float tot_s[Nn];
    __shared__ float rv[256];
    __shared__ int   ri[256];

    const int bm = blockIdx.x;
    const int b  = bm / Mm;
    const int tid = threadIdx.x;
    const float iw = read_dim(wp);
    const float ih = read_dim(hp);

    if (!mask_at(masks, hdr->mask_mode, bm)) {
        if (tid == 0) dynk[bm] = 0;
        return;
    }
    if (tid < Ss)
        ys[tid] = (float)((double)(ih - 1.0f) * (double)(Ss - 1 - tid) / (double)(Ss - 1));
    __syncthreads();

    const float* tg = targs + (size_t)bm * Cc;
    const float g_sy = tg[2], g_sx = tg[3], g_th = tg[4];
    const float g_tan = fminf(fmaxf(tanf(g_th * DEG2RAD), -1000.0f), 1000.0f);
    if (tid < Ss) {
        float gdx = tg[6 + tid];
        float v = g_sx + (g_sy - ys[tid]) * g_tan + gdx;
        if (gdx < -10000.0f || v < 0.0f || v >= iw) v = INVALIDF;
        gx[tid] = v;
    }
    __syncthreads();

    for (int n = tid; n < Nn; n += 256) {
        const float* pr = preds + ((size_t)b * Nn + n) * Cc;
        const float p0 = pr[0], p1 = pr[1];
        const float sy = pr[2], sx = pr[3], th = pr[4], len = pr[5];
        const float mx = fmaxf(p0, p1);
        const float e0 = expf(p0 - mx), e1 = expf(p1 - mx);
        float score = fmaxf(e1 / (e0 + e1), 1e-8f);
        const float cls = -logf(score);
        const float ptan = fminf(fmaxf(tanf(th * DEG2RAD), -1000.0f), 1000.0f);
        const float lo = sy - len;
        float ov = 0.0f, un = 0.0f;
        for (int s = 0; s < Ss; ++s) {
            const float y = ys[s];
            const float t = gx[s];
            if (y >= lo && y <= sy && t != INVALIDF) {
                const float px = sx + (sy - y) * ptan + pr[6 + s];
                if (px != INVALIDF) {
                    const float d = fabsf(px - t);
                    ov += 30.0f - d;
                    un += 30.0f + d;
                }
            }
        }
        const float iou = ov / (un + 1e-9f);
        const float dxn = (sx - g_sx) / (iw - 1.0f);
        const float dyn = (sy - g_sy) / (ih - 1.0f);
        const float dist = sqrtf(dxn * dxn + dyn * dyn + 1e-8f);
        const float theta = fabsf((th - g_th) / 90.0f);
        const float tot = 4.0f * cls + 5.0f * (1.0f * dist + 2.0f * theta) + 2.0f * (1.0f - iou);
        iou_s[n] = iou;
        tot_s[n] = tot;
    }
    __syncthreads();

    for (int k = 0; k < Kk; ++k) {
        float bv = FLT_MAX; int bi = 0x7fffffff;
        for (int n = tid; n < Nn; n += 256) {
            const float v = tot_s[n];
            if (v < bv) { bv = v; bi = n; }
        }
        rv[tid] = bv; ri[tid] = bi;
        __syncthreads();
        for (int off = 128; off > 0; off >>= 1) {
            if (tid < off) {
                const float v2 = rv[tid + off]; const int i2 = ri[tid + off];
                if (v2 < rv[tid] || (v2 == rv[tid] && i2 < ri[tid])) { rv[tid] = v2; ri[tid] = i2; }
            }
            __syncthreads();
        }
        if (tid == 0) {
            const int c = ri[0];
            selk[bm * Kk + k] = c;
            seltot[bm * Kk + k] = tot_s[c];
            tot_s[c] = FLT_MAX;
        }
        __syncthreads();
    }

    float isum = 0.0f;
    for (int k = 0; k < Kk; ++k) {
        float bv = -FLT_MAX; int bi = 0x7fffffff;
        for (int n = tid; n < Nn; n += 256) {
            const float v = iou_s[n];
            if (v > bv) { bv = v; bi = n; }
        }
        rv[tid] = bv; ri[tid] = bi;
        __syncthreads();
        for (int off = 128; off > 0; off >>= 1) {
            if (tid < off) {
                const float v2 = rv[tid + off]; const int i2 = ri[tid + off];
                if (v2 > rv[tid] || (v2 == rv[tid] && i2 < ri[tid])) { rv[tid] = v2; ri[tid] = i2; }
            }
            __syncthreads();
        }
        if (tid == 0) {
            const int c = ri[0];
            isum += iou_s[c];
            iou_s[c] = -FLT_MAX;
        }
        __syncthreads();
    }
    if (tid == 0) {
        int dk = (int)isum;
        dk = (dk < 1) ? 1 : (dk > Nn ? Nn : dk);
        dynk[bm] = dk;
    }
}

__global__ __launch_bounds__(256) void k_resolve_fb(
    const int* __restrict__ selk, const float* __restrict__ seltot,
    const int* __restrict__ dynk, int* __restrict__ out)
{
    const int gid = blockIdx.x * 256 + threadIdx.x;
    if (gid >= Bb * Nn) return;
    const int b = gid / Nn;
    const int n = gid % Nn;

    int cnt = 0, firstm = -1, bestm = -1;
    float bestv = FLT_MAX;
    for (int m = 0; m < Mm; ++m) {
        const int bm = b * Mm + m;
        const int dk = dynk[bm];
        for (int k = 0; k < dk && k < Kk; ++k) {
            if (selk[bm * Kk + k] == n) {
                const float tv = seltot[bm * Kk + k];
                cnt++;
                if (firstm < 0) firstm = m;
                if (tv < bestv) { bestv = tv; bestm = m; }
                break;
            }
        }
    }
    int matched;
    if (cnt == 0)      matched = -1;
    else if (cnt == 1) matched = firstm;
    else               matched = bestm;

    out[gid]           = (cnt > 0) ? 1 : 0;
    out[Bb * Nn + gid] = matched;
}

extern "C" void kernel_launch(void* const* d_in, const int* in_sizes, int n_in,
                              void* d_out, int out_size, void* d_ws, size_t ws_size,
                              hipStream_t stream) {
    const float* preds = (const float*)d_in[0];
    const float* targs = (const float*)d_in[1];
    const void*  masks = d_in[2];
    const void*  wp    = d_in[3];
    const void*  hp    = d_in[4];
    int* out = (int*)d_out;

    char* ws = (char*)d_ws;
    Hdr* hdr = (Hdr*)ws;

    if (ws_size >= (size_t)WS6_NEEDED) {
        float*  chtot = (float*)(ws + OFF_CHTOT);
        int*    chidx = (int*)(ws + OFF_CHIDX);
        float*  chiou = (float*)(ws + OFF_CHIOU);
        float4* pmeta = (float4*)(ws + OFF_PMETA);
        float*  pxs   = (float*)(ws + OFF_PXS);

        k_prep2<<<512, 256, 0, stream>>>(preds, (const unsigned char*)masks, hp,
                                         hdr, pxs, pmeta);
        k_colE3<<<Bb * Mm * NCH, 256, 0, stream>>>(targs, masks, hdr, pxs, pmeta,
                                                   wp, hp, chtot, chidx, chiou);
        k_final<<<Bb, 1024, 0, stream>>>(masks, hdr, chtot, chidx, chiou, out);
    } else {
        int*   selk   = (int*)(ws + OFF_FSELK);
        float* seltot = (float*)(ws + OFF_FSELTOT);
        int*   dynk   = (int*)(ws + OFF_FDYNK);
        k_detect_fb<<<1, 1, 0, stream>>>((const unsigned char*)masks, hdr);
        k_col_fb<<<Bb * Mm, 256, 0, stream>>>(preds, targs, masks, hdr, wp, hp,
                                              selk, seltot, dynk);
        k_resolve_fb<<<(Bb * Nn + 255) / 256, 256, 0, stream>>>(selk, seltot, dynk, out);
    }
}